// Round 1
// baseline (986.197 us; speedup 1.0000x reference)
//
#include <hip/hip_runtime.h>
#include <hip/hip_bf16.h>

// Problem constants (match reference)
#define AG 8            // agents
#define BT 2048         // batch
#define RT (AG*BT)      // 16384 total rows
#define NNET 4          // networks
#define D0 128
#define H1 1024
#define H2 1024
#define H3 512

// GEMM tiling
#define BM 64
#define BN 64
#define BK 32
#define NTHR 256

__device__ __forceinline__ float bf2f(unsigned short u){
  unsigned int x = ((unsigned int)u) << 16;
  return __uint_as_float(x);
}
__device__ __forceinline__ unsigned short f2bf(float f){
  unsigned int x = __float_as_uint(f);
  x += 0x7fff + ((x >> 16) & 1);   // round-to-nearest-even
  return (unsigned short)(x >> 16);
}

__global__ void k_init(int* counts){
  if (threadIdx.x < NNET) counts[threadIdx.x] = 0;
}

// Bucket rows by network id. Order within bucket is nondeterministic (atomics),
// but each row's math is position-independent -> final output deterministic.
__global__ void k_compact(const int* __restrict__ seps, int* __restrict__ counts,
                          int* __restrict__ rowlist){
  int t = blockIdx.x * blockDim.x + threadIdx.x;
  if (t >= RT) return;
  int a = t / BT, b = t - a*BT;         // row t == (a,b), inputs row-major [A,B,D]
  int n = seps[b*AG + a];               // seps_indices is [B,A]
  int pos = atomicAdd(&counts[n], 1);
  rowlist[n*RT + pos] = t;
}

__global__ void k_prefix(const int* __restrict__ counts, int* __restrict__ offsets){
  int s = 0;
  for (int i = 0; i < NNET; i++){ offsets[i] = s; s += counts[i]; }
}

// One tiled GEMM layer over a network bucket.
// GATHER_IN:  A rows gathered from fp32 inputs via rowlist.
// !GATHER_IN: A rows read contiguously from bf16 h buffer at compacted positions.
// SCATTER_OUT: write fp32 to d_out via rowlist; else write bf16 h compacted.
template<int K, int NOUT, int RELU, int GATHER_IN, int SCATTER_OUT>
__global__ __launch_bounds__(NTHR) void k_layer(
    const float* __restrict__ Xf,
    const unsigned short* __restrict__ Xh,
    const float* __restrict__ W,      // [NNET, K, NOUT]
    const float* __restrict__ Bias,   // [NNET, NOUT]
    const int* __restrict__ counts,
    const int* __restrict__ offsets,
    const int* __restrict__ rowlist,  // [NNET, RT]
    unsigned short* __restrict__ Yh,  // bf16 compacted out
    float* __restrict__ Yf)           // fp32 scatter out
{
  const int n   = blockIdx.z;
  const int cnt = counts[n];
  const int i0  = blockIdx.x * BM;
  if (i0 >= cnt) return;              // uniform across block
  const int off = offsets[n];
  const int bn  = blockIdx.y * BN;
  const int t   = threadIdx.x;

  __shared__ __align__(16) float As[BK][BM+4];   // transposed A tile: [k][m]
  __shared__ __align__(16) float Bs[BK][BN+4];
  __shared__ int rs[BM];

  if (t < BM){
    int i = i0 + t;
    rs[t] = (i < cnt) ? rowlist[n*RT + i] : -1;
  }
  __syncthreads();

  const float* Wn = W + (size_t)n * K * NOUT;
  float acc[4][4] = {{0.f}};

  for (int k0 = 0; k0 < K; k0 += BK){
    // ---- stage A tile (BM x BK), write transposed into As[k][m]
    #pragma unroll
    for (int ld = 0; ld < 2; ld++){
      int f  = t + ld*NTHR;           // 512 float4-slots: row = f/8, 8 x float4 per row
      int r  = f >> 3;
      int c4 = (f & 7) << 2;
      float4 v = make_float4(0.f,0.f,0.f,0.f);
      if (GATHER_IN){
        int orig = rs[r];
        if (orig >= 0) v = *(const float4*)(Xf + (size_t)orig*K + k0 + c4);
      } else {
        if (i0 + r < cnt){
          const unsigned short* p = Xh + (size_t)(off + i0 + r)*K + k0 + c4;
          ushort4 u = *(const ushort4*)p;
          v.x = bf2f(u.x); v.y = bf2f(u.y); v.z = bf2f(u.z); v.w = bf2f(u.w);
        }
      }
      As[c4+0][r] = v.x; As[c4+1][r] = v.y; As[c4+2][r] = v.z; As[c4+3][r] = v.w;
    }
    // ---- stage B tile (BK x BN) from W, natural layout, float4
    #pragma unroll
    for (int ld = 0; ld < 2; ld++){
      int f  = t + ld*NTHR;           // 512 float4-slots: row = f/16, 16 x float4 per row
      int r  = f >> 4;
      int c4 = (f & 15) << 2;
      *(float4*)&Bs[r][c4] = *(const float4*)(Wn + (size_t)(k0 + r)*NOUT + bn + c4);
    }
    __syncthreads();

    const int ty = t >> 4, tx = t & 15;
    #pragma unroll
    for (int kk = 0; kk < BK; kk++){
      float a4[4], b4[4];
      *(float4*)a4 = *(const float4*)&As[kk][ty<<2];   // ds_read_b128
      *(float4*)b4 = *(const float4*)&Bs[kk][tx<<2];   // ds_read_b128
      #pragma unroll
      for (int i = 0; i < 4; i++)
        #pragma unroll
        for (int j = 0; j < 4; j++)
          acc[i][j] = fmaf(a4[i], b4[j], acc[i][j]);
    }
    __syncthreads();
  }

  // ---- epilogue
  const int ty = t >> 4, tx = t & 15;
  float bv[4];
  *(float4*)bv = *(const float4*)(Bias + n*NOUT + bn + (tx<<2));
  #pragma unroll
  for (int i = 0; i < 4; i++){
    int ri = (ty<<2) + i;
    int gi = i0 + ri;
    if (gi < cnt){
      float o[4];
      #pragma unroll
      for (int j = 0; j < 4; j++){
        float v = acc[i][j] + bv[j];
        if (RELU) v = fmaxf(v, 0.f);
        o[j] = v;
      }
      if (SCATTER_OUT){
        int orig = rs[ri];
        *(float4*)(Yf + (size_t)orig*NOUT + bn + (tx<<2)) = make_float4(o[0],o[1],o[2],o[3]);
      } else {
        ushort4 u;
        u.x = f2bf(o[0]); u.y = f2bf(o[1]); u.z = f2bf(o[2]); u.w = f2bf(o[3]);
        *(ushort4*)(Yh + (size_t)(off + gi)*NOUT + bn + (tx<<2)) = u;
      }
    }
  }
}

extern "C" void kernel_launch(void* const* d_in, const int* in_sizes, int n_in,
                              void* d_out, int out_size, void* d_ws, size_t ws_size,
                              hipStream_t stream) {
  const float* inputs = (const float*)d_in[0];   // [A,B,D] f32
  const int*   seps   = (const int*)  d_in[1];   // [B,A] i32
  const float* W0     = (const float*)d_in[2];   // [N,D,H1]
  const float* b0     = (const float*)d_in[3];
  const float* W1     = (const float*)d_in[4];   // [N,H1,H2]
  const float* b1     = (const float*)d_in[5];
  const float* W2     = (const float*)d_in[6];   // [N,H2,H3]
  const float* b2     = (const float*)d_in[7];
  float* out = (float*)d_out;                    // [A,B,H3] f32

  // ws layout: counts[4] | offsets[4] | pad | rowlist[N*RT] | h1 bf16 | h2 bf16
  char* ws = (char*)d_ws;
  int* counts  = (int*)ws;
  int* offsets = counts + 4;
  int* rowlist = (int*)(ws + 256);                               // 256 KiB
  unsigned short* h1 = (unsigned short*)(ws + 262400);           // RT*H1 bf16 = 32 MiB
  unsigned short* h2 = h1 + (size_t)RT * H1;                     // RT*H2 bf16 = 32 MiB
  // total ws use: ~64.3 MiB

  k_init   <<<1, 64, 0, stream>>>(counts);
  k_compact<<<RT/256, 256, 0, stream>>>(seps, counts, rowlist);
  k_prefix <<<1, 1, 0, stream>>>(counts, offsets);

  dim3 blk(NTHR);
  // Layer 0: [rows,128] x [128,1024] + relu -> h1 (bf16)
  k_layer<D0, H1, 1, 1, 0><<<dim3(RT/BM, H1/BN, NNET), blk, 0, stream>>>(
      inputs, nullptr, W0, b0, counts, offsets, rowlist, h1, nullptr);
  // Layer 1: [rows,1024] x [1024,1024] + relu -> h2 (bf16)
  k_layer<H1, H2, 1, 0, 0><<<dim3(RT/BM, H2/BN, NNET), blk, 0, stream>>>(
      nullptr, h1, W1, b1, counts, offsets, rowlist, h2, nullptr);
  // Layer 2: [rows,1024] x [1024,512] -> scatter fp32 to out
  k_layer<H2, H3, 0, 0, 1><<<dim3(RT/BM, H3/BN, NNET), blk, 0, stream>>>(
      nullptr, h2, W2, b2, counts, offsets, rowlist, nullptr, out);
}

// Round 2
// 240.862 us; speedup vs baseline: 4.0944x; 4.0944x over previous
//
#include <hip/hip_runtime.h>
#include <hip/hip_bf16.h>

// Problem constants
#define AG 8
#define BT 2048
#define RT (AG*BT)      // 16384 rows
#define NNET 4
#define D0 128
#define H1 1024
#define H2 1024
#define H3 512

typedef __attribute__((ext_vector_type(8))) short short8;
typedef __attribute__((ext_vector_type(4))) float f32x4;

__device__ __forceinline__ float bf2f(unsigned short u){
  return __uint_as_float(((unsigned int)u) << 16);
}
__device__ __forceinline__ unsigned short f2bf(float f){
  unsigned int x = __float_as_uint(f);
  x += 0x7fff + ((x >> 16) & 1);   // RNE
  return (unsigned short)(x >> 16);
}

__device__ __forceinline__ void gload_lds16(const void* g, void* l){
  __builtin_amdgcn_global_load_lds(
      (const __attribute__((address_space(1))) unsigned int*)g,
      (__attribute__((address_space(3))) unsigned int*)l, 16, 0, 0);
}

__global__ void k_init(int* counts){
  if (threadIdx.x < NNET) counts[threadIdx.x] = 0;
}

__global__ void k_compact(const int* __restrict__ seps, int* __restrict__ counts,
                          int* __restrict__ rowlist){
  int t = blockIdx.x * blockDim.x + threadIdx.x;
  if (t >= RT) return;
  int a = t / BT, b = t - a*BT;
  int n = seps[b*AG + a];               // seps_indices is [B,A]
  int pos = atomicAdd(&counts[n], 1);
  rowlist[n*RT + pos] = t;
}

__global__ void k_prefix(const int* __restrict__ counts, int* __restrict__ offsets){
  int s = 0;
  for (int i = 0; i < NNET; i++){ offsets[i] = s; s += counts[i]; }
}

// W[n][K][NOUT] f32 -> WT[n][NOUT][K] bf16
template<int K, int NOUT>
__global__ __launch_bounds__(256) void k_transpose(const float* __restrict__ W,
                                                   unsigned short* __restrict__ WT){
  __shared__ float tile[32][33];
  int n = blockIdx.z;
  int k0 = blockIdx.x*32, o0 = blockIdx.y*32;
  const float* Wn = W + (size_t)n*K*NOUT;
  unsigned short* WTn = WT + (size_t)n*NOUT*K;
  int tx = threadIdx.x & 31, ty0 = threadIdx.x >> 5;
  #pragma unroll
  for (int r = 0; r < 32; r += 8)
    tile[ty0 + r][tx] = Wn[(size_t)(k0 + ty0 + r)*NOUT + o0 + tx];
  __syncthreads();
  #pragma unroll
  for (int r = 0; r < 32; r += 8)
    WTn[(size_t)(o0 + ty0 + r)*K + k0 + tx] = f2bf(tile[tx][ty0 + r]);
}

// gather fp32 input rows -> compacted bf16 X0h[RT][D0]
__global__ __launch_bounds__(256) void k_gather0(const float* __restrict__ X,
                          const int* __restrict__ counts, const int* __restrict__ offsets,
                          const int* __restrict__ rowlist, unsigned short* __restrict__ X0h){
  int n = blockIdx.y;
  int cnt = counts[n];
  int i = blockIdx.x*16 + (threadIdx.x >> 4);
  if (i >= cnt) return;
  int orig = rowlist[n*RT + i];
  int c = (threadIdx.x & 15) * 8;
  const float* src = X + (size_t)orig*D0 + c;
  float4 v0 = *(const float4*)src, v1 = *(const float4*)(src+4);
  ushort4 u0, u1;
  u0.x=f2bf(v0.x); u0.y=f2bf(v0.y); u0.z=f2bf(v0.z); u0.w=f2bf(v0.w);
  u1.x=f2bf(v1.x); u1.y=f2bf(v1.y); u1.z=f2bf(v1.z); u1.w=f2bf(v1.w);
  unsigned short* dst = X0h + (size_t)(offsets[n] + i)*D0 + c;
  *(ushort4*)dst = u0; *(ushort4*)(dst+4) = u1;
}

// MFMA GEMM over one network bucket: C[rows, NOUT] = X[rows,K] * WT[NOUT,K]^T + bias
// 128x128 tile, BK=32, 4 waves (2x2), 64x64 per wave, 16x16x32 bf16 MFMA.
// LDS linear dest for global_load_lds; 16B-slot XOR swizzle (slot ^= (row>>1)&3)
// applied to BOTH the global source and the ds_read address (rule #21).
template<int K, int NOUT, int RELU, int SCATTER>
__global__ __launch_bounds__(256) void k_mlp(
    const unsigned short* __restrict__ X,   // compacted bf16 [RT, K]
    const unsigned short* __restrict__ WT,  // [N, NOUT, K] bf16
    const float* __restrict__ Bias,         // [N, NOUT] f32
    const int* __restrict__ counts, const int* __restrict__ offsets,
    const int* __restrict__ rowlist,
    unsigned short* __restrict__ Yh,        // compacted bf16 out
    float* __restrict__ Yf)                 // scatter f32 out
{
  const int n = blockIdx.z;
  const int cnt = counts[n];
  const int i0 = blockIdx.x * 128;
  if (i0 >= cnt) return;
  const int off = offsets[n];
  const int bn = blockIdx.y * 128;

  __shared__ __align__(16) unsigned short As[128*32];
  __shared__ __align__(16) unsigned short Bs[128*32];
  __shared__ int rs[128];

  const int t = threadIdx.x, lane = t & 63, wave = t >> 6;
  const int wm = wave >> 1, wn = wave & 1;
  const int lr = lane & 15, g = lane >> 4;

  if (SCATTER && t < 128) rs[t] = rowlist[n*RT + min(i0 + t, cnt-1)];

  // staging: per K-step, A tile 128x32 bf16 (8KB) + B tile 8KB; 2 issues each
  const unsigned short* pA[2]; const unsigned short* pB[2];
  unsigned int ldsoff[2];
  const unsigned short* WTn = WT + (size_t)n * NOUT * K;
  #pragma unroll
  for (int j = 0; j < 2; j++){
    int r  = (j*4 + wave)*16 + (lane >> 2);   // tile row this lane fills
    int ps = lane & 3;                        // physical 16B slot
    int ls = ps ^ ((r >> 1) & 3);             // logical slot (inverse swizzle)
    int rA = min(i0 + r, cnt-1);
    pA[j] = X   + (size_t)(off + rA)*K + ls*8;
    pB[j] = WTn + (size_t)(bn  + r )*K + ls*8;
    ldsoff[j] = (unsigned)(j*4 + wave) * 512; // ushort elements (1KB per wave-issue)
  }

  // fragment ds_read offsets (swizzled)
  int aoff[4], boff[4];
  #pragma unroll
  for (int i = 0; i < 4; i++){
    int ra = wm*64 + i*16 + lr;
    aoff[i] = ra*32 + (g ^ ((ra>>1)&3))*8;
    int rb = wn*64 + i*16 + lr;
    boff[i] = rb*32 + (g ^ ((rb>>1)&3))*8;
  }

  f32x4 acc[4][4] = {};
  for (int k0 = 0; k0 < K; k0 += 32){
    #pragma unroll
    for (int j = 0; j < 2; j++){
      gload_lds16(pA[j], &As[ldsoff[j]]);
      gload_lds16(pB[j], &Bs[ldsoff[j]]);
      pA[j] += 32; pB[j] += 32;
    }
    __syncthreads();   // drains vmcnt (global_load_lds) + orders LDS

    short8 av[4], bv[4];
    #pragma unroll
    for (int i = 0; i < 4; i++) av[i] = *(const short8*)&As[aoff[i]];
    #pragma unroll
    for (int i = 0; i < 4; i++) bv[i] = *(const short8*)&Bs[boff[i]];
    #pragma unroll
    for (int mi = 0; mi < 4; mi++)
      #pragma unroll
      for (int ni = 0; ni < 4; ni++)
        acc[mi][ni] = __builtin_amdgcn_mfma_f32_16x16x32_bf16(av[mi], bv[ni], acc[mi][ni], 0, 0, 0);
    __syncthreads();
  }

  // epilogue: D layout col=lane&15, row=(lane>>4)*4+reg (m89-verified)
  float bias4[4];
  #pragma unroll
  for (int ni = 0; ni < 4; ni++)
    bias4[ni] = Bias[n*NOUT + bn + wn*64 + ni*16 + lr];

  #pragma unroll
  for (int mi = 0; mi < 4; mi++){
    #pragma unroll
    for (int i = 0; i < 4; i++){
      int rloc = wm*64 + mi*16 + g*4 + i;
      int grow = i0 + rloc;
      if (grow < cnt){
        #pragma unroll
        for (int ni = 0; ni < 4; ni++){
          float v = acc[mi][ni][i] + bias4[ni];
          if (RELU) v = fmaxf(v, 0.f);
          int col = bn + wn*64 + ni*16 + lr;
          if (SCATTER) Yf[(size_t)rs[rloc]*NOUT + col] = v;
          else         Yh[(size_t)(off + grow)*NOUT + col] = f2bf(v);
        }
      }
    }
  }
}

extern "C" void kernel_launch(void* const* d_in, const int* in_sizes, int n_in,
                              void* d_out, int out_size, void* d_ws, size_t ws_size,
                              hipStream_t stream) {
  const float* inputs = (const float*)d_in[0];
  const int*   seps   = (const int*)  d_in[1];
  const float* W0     = (const float*)d_in[2];
  const float* b0     = (const float*)d_in[3];
  const float* W1     = (const float*)d_in[4];
  const float* b1     = (const float*)d_in[5];
  const float* W2     = (const float*)d_in[6];
  const float* b2     = (const float*)d_in[7];
  float* out = (float*)d_out;

  // ws layout (78 MiB):
  // 0: counts/offsets | 4K: rowlist(256K) | 1M: WT0(1M) | 2M: WT1(8M) | 10M: WT2(4M)
  // 14M: h1(32M) | 46M: h2(32M), X0h(4M) overlaps h2 start (disjoint lifetimes)
  char* ws = (char*)d_ws;
  int* counts  = (int*)ws;
  int* offsets = counts + 4;
  int* rowlist = (int*)(ws + 4096);
  const size_t MB = 1u << 20;
  unsigned short* WT0 = (unsigned short*)(ws + 1*MB);
  unsigned short* WT1 = (unsigned short*)(ws + 2*MB);
  unsigned short* WT2 = (unsigned short*)(ws + 10*MB);
  unsigned short* h1  = (unsigned short*)(ws + 14*MB);
  unsigned short* h2  = (unsigned short*)(ws + 46*MB);
  unsigned short* X0h = (unsigned short*)(ws + 46*MB);  // dead before h2 written

  k_init   <<<1, 64, 0, stream>>>(counts);
  k_compact<<<RT/256, 256, 0, stream>>>(seps, counts, rowlist);
  k_prefix <<<1, 1, 0, stream>>>(counts, offsets);

  k_transpose<D0, H1><<<dim3(D0/32, H1/32, NNET), 256, 0, stream>>>(W0, WT0);
  k_transpose<H1, H2><<<dim3(H1/32, H2/32, NNET), 256, 0, stream>>>(W1, WT1);
  k_transpose<H2, H3><<<dim3(H2/32, H3/32, NNET), 256, 0, stream>>>(W2, WT2);
  k_gather0<<<dim3(RT/16, NNET), 256, 0, stream>>>(inputs, counts, offsets, rowlist, X0h);

  k_mlp<D0, H1, 1, 0><<<dim3(RT/128, H1/128, NNET), 256, 0, stream>>>(
      X0h, WT0, b0, counts, offsets, rowlist, h1, nullptr);
  k_mlp<H1, H2, 1, 0><<<dim3(RT/128, H2/128, NNET), 256, 0, stream>>>(
      h1, WT1, b1, counts, offsets, rowlist, h2, nullptr);
  k_mlp<H2, H3, 0, 1><<<dim3(RT/128, H3/128, NNET), 256, 0, stream>>>(
      h2, WT2, b2, counts, offsets, rowlist, nullptr, out);
}

// Round 3
// 152.173 us; speedup vs baseline: 6.4808x; 1.5828x over previous
//
#include <hip/hip_runtime.h>
#include <hip/hip_bf16.h>

// Problem constants
#define AG 8
#define BT 2048
#define RT (AG*BT)      // 16384 rows
#define NNET 4
#define D0 128
#define H1 1024
#define H2 1024
#define H3 512

typedef __attribute__((ext_vector_type(8))) short short8;
typedef __attribute__((ext_vector_type(4))) float f32x4;

__device__ __forceinline__ float bf2f(unsigned short u){
  return __uint_as_float(((unsigned int)u) << 16);
}
__device__ __forceinline__ unsigned short f2bf(float f){
  unsigned int x = __float_as_uint(f);
  x += 0x7fff + ((x >> 16) & 1);   // RNE
  return (unsigned short)(x >> 16);
}

__device__ __forceinline__ void gload_lds16(const void* g, void* l){
  __builtin_amdgcn_global_load_lds(
      (const __attribute__((address_space(1))) unsigned int*)g,
      (__attribute__((address_space(3))) unsigned int*)l, 16, 0, 0);
}

// exclusive prefix of counts[0..n-1]
__device__ __forceinline__ int bucket_off(const int* counts, int n){
  int s = 0;
  #pragma unroll
  for (int i = 0; i < NNET-1; i++) if (i < n) s += counts[i];
  return s;
}

__global__ void k_init(int* counts){
  if (threadIdx.x < NNET) counts[threadIdx.x] = 0;
}

// Hierarchical compaction: LDS-local rank + one global atomicAdd per (block,net).
// 256 global atomics total instead of 16384 -> no L2 serialization elephant.
__global__ __launch_bounds__(256) void k_compact(const int* __restrict__ seps,
                          int* __restrict__ counts, int* __restrict__ rowlist){
  __shared__ int lcount[NNET];
  __shared__ int lbase[NNET];
  int t = blockIdx.x * 256 + threadIdx.x;
  if (threadIdx.x < NNET) lcount[threadIdx.x] = 0;
  __syncthreads();
  int a = t >> 11, b = t & (BT-1);      // row t == (a,b)
  int n = seps[b*AG + a];               // seps_indices is [B,A]
  int lrank = atomicAdd(&lcount[n], 1);
  __syncthreads();
  if (threadIdx.x < NNET)
    lbase[threadIdx.x] = atomicAdd(&counts[threadIdx.x], lcount[threadIdx.x]);
  __syncthreads();
  rowlist[n*RT + lbase[n] + lrank] = t;
}

// W[n][K][NOUT] f32 -> WT[n][NOUT][K] bf16
template<int K, int NOUT>
__global__ __launch_bounds__(256) void k_transpose(const float* __restrict__ W,
                                                   unsigned short* __restrict__ WT){
  __shared__ float tile[32][33];
  int n = blockIdx.z;
  int k0 = blockIdx.x*32, o0 = blockIdx.y*32;
  const float* Wn = W + (size_t)n*K*NOUT;
  unsigned short* WTn = WT + (size_t)n*NOUT*K;
  int tx = threadIdx.x & 31, ty0 = threadIdx.x >> 5;
  #pragma unroll
  for (int r = 0; r < 32; r += 8)
    tile[ty0 + r][tx] = Wn[(size_t)(k0 + ty0 + r)*NOUT + o0 + tx];
  __syncthreads();
  #pragma unroll
  for (int r = 0; r < 32; r += 8)
    WTn[(size_t)(o0 + ty0 + r)*K + k0 + tx] = f2bf(tile[tx][ty0 + r]);
}

// gather fp32 input rows -> compacted bf16 X0h[RT][D0]
__global__ __launch_bounds__(256) void k_gather0(const float* __restrict__ X,
                          const int* __restrict__ counts,
                          const int* __restrict__ rowlist, unsigned short* __restrict__ X0h){
  int n = blockIdx.y;
  int cnt = counts[n];
  int i = blockIdx.x*16 + (threadIdx.x >> 4);
  if (i >= cnt) return;
  int off = bucket_off(counts, n);
  int orig = rowlist[n*RT + i];
  int c = (threadIdx.x & 15) * 8;
  const float* src = X + (size_t)orig*D0 + c;
  float4 v0 = *(const float4*)src, v1 = *(const float4*)(src+4);
  ushort4 u0, u1;
  u0.x=f2bf(v0.x); u0.y=f2bf(v0.y); u0.z=f2bf(v0.z); u0.w=f2bf(v0.w);
  u1.x=f2bf(v1.x); u1.y=f2bf(v1.y); u1.z=f2bf(v1.z); u1.w=f2bf(v1.w);
  unsigned short* dst = X0h + (size_t)(off + i)*D0 + c;
  *(ushort4*)dst = u0; *(ushort4*)(dst+4) = u1;
}

// MFMA GEMM over one network bucket: C[rows, NOUT] = X[rows,K] * WT[NOUT,K]^T + bias
// 128x128 tile, BK=32, 4 waves (2x2), 64x64 per wave, 16x16x32 bf16 MFMA.
// LDS linear dest for global_load_lds; 16B-slot XOR swizzle (slot ^= (row>>1)&3)
// applied to BOTH the global source and the ds_read address (rule #21).
template<int K, int NOUT, int RELU, int SCATTER>
__global__ __launch_bounds__(256) void k_mlp(
    const unsigned short* __restrict__ X,   // compacted bf16 [RT, K]
    const unsigned short* __restrict__ WT,  // [N, NOUT, K] bf16
    const float* __restrict__ Bias,         // [N, NOUT] f32
    const int* __restrict__ counts,
    const int* __restrict__ rowlist,
    unsigned short* __restrict__ Yh,        // compacted bf16 out
    float* __restrict__ Yf)                 // scatter f32 out
{
  const int n = blockIdx.z;
  const int cnt = counts[n];
  const int i0 = blockIdx.x * 128;
  if (i0 >= cnt) return;
  const int off = bucket_off(counts, n);
  const int bn = blockIdx.y * 128;

  __shared__ __align__(16) unsigned short As[128*32];
  __shared__ __align__(16) unsigned short Bs[128*32];
  __shared__ int rs[128];

  const int t = threadIdx.x, lane = t & 63, wave = t >> 6;
  const int wm = wave >> 1, wn = wave & 1;
  const int lr = lane & 15, g = lane >> 4;

  if (SCATTER && t < 128) rs[t] = rowlist[n*RT + min(i0 + t, cnt-1)];

  // staging: per K-step, A tile 128x32 bf16 (8KB) + B tile 8KB; 2 issues each
  const unsigned short* pA[2]; const unsigned short* pB[2];
  unsigned int ldsoff[2];
  const unsigned short* WTn = WT + (size_t)n * NOUT * K;
  #pragma unroll
  for (int j = 0; j < 2; j++){
    int r  = (j*4 + wave)*16 + (lane >> 2);   // tile row this lane fills
    int ps = lane & 3;                        // physical 16B slot
    int ls = ps ^ ((r >> 1) & 3);             // logical slot (inverse swizzle)
    int rA = min(i0 + r, cnt-1);
    pA[j] = X   + (size_t)(off + rA)*K + ls*8;
    pB[j] = WTn + (size_t)(bn  + r )*K + ls*8;
    ldsoff[j] = (unsigned)(j*4 + wave) * 512; // ushort elements (1KB per wave-issue)
  }

  // fragment ds_read offsets (swizzled)
  int aoff[4], boff[4];
  #pragma unroll
  for (int i = 0; i < 4; i++){
    int ra = wm*64 + i*16 + lr;
    aoff[i] = ra*32 + (g ^ ((ra>>1)&3))*8;
    int rb = wn*64 + i*16 + lr;
    boff[i] = rb*32 + (g ^ ((rb>>1)&3))*8;
  }

  f32x4 acc[4][4] = {};
  for (int k0 = 0; k0 < K; k0 += 32){
    #pragma unroll
    for (int j = 0; j < 2; j++){
      gload_lds16(pA[j], &As[ldsoff[j]]);
      gload_lds16(pB[j], &Bs[ldsoff[j]]);
      pA[j] += 32; pB[j] += 32;
    }
    __syncthreads();   // drains vmcnt (global_load_lds) + orders LDS

    short8 av[4], bv[4];
    #pragma unroll
    for (int i = 0; i < 4; i++) av[i] = *(const short8*)&As[aoff[i]];
    #pragma unroll
    for (int i = 0; i < 4; i++) bv[i] = *(const short8*)&Bs[boff[i]];
    #pragma unroll
    for (int mi = 0; mi < 4; mi++)
      #pragma unroll
      for (int ni = 0; ni < 4; ni++)
        acc[mi][ni] = __builtin_amdgcn_mfma_f32_16x16x32_bf16(av[mi], bv[ni], acc[mi][ni], 0, 0, 0);
    __syncthreads();
  }

  // epilogue: D layout col=lane&15, row=(lane>>4)*4+reg (m89-verified)
  float bias4[4];
  #pragma unroll
  for (int ni = 0; ni < 4; ni++)
    bias4[ni] = Bias[n*NOUT + bn + wn*64 + ni*16 + lr];

  #pragma unroll
  for (int mi = 0; mi < 4; mi++){
    #pragma unroll
    for (int i = 0; i < 4; i++){
      int rloc = wm*64 + mi*16 + g*4 + i;
      int grow = i0 + rloc;
      if (grow < cnt){
        #pragma unroll
        for (int ni = 0; ni < 4; ni++){
          float v = acc[mi][ni][i] + bias4[ni];
          if (RELU) v = fmaxf(v, 0.f);
          int col = bn + wn*64 + ni*16 + lr;
          if (SCATTER) Yf[(size_t)rs[rloc]*NOUT + col] = v;
          else         Yh[(size_t)(off + grow)*NOUT + col] = f2bf(v);
        }
      }
    }
  }
}

extern "C" void kernel_launch(void* const* d_in, const int* in_sizes, int n_in,
                              void* d_out, int out_size, void* d_ws, size_t ws_size,
                              hipStream_t stream) {
  const float* inputs = (const float*)d_in[0];
  const int*   seps   = (const int*)  d_in[1];
  const float* W0     = (const float*)d_in[2];
  const float* b0     = (const float*)d_in[3];
  const float* W1     = (const float*)d_in[4];
  const float* b1     = (const float*)d_in[5];
  const float* W2     = (const float*)d_in[6];
  const float* b2     = (const float*)d_in[7];
  float* out = (float*)d_out;

  // ws layout (78 MiB):
  // 0: counts | 4K: rowlist(256K) | 1M: WT0(1M) | 2M: WT1(8M) | 10M: WT2(4M)
  // 14M: h1(32M) | 46M: h2(32M), X0h(4M) overlaps h2 start (disjoint lifetimes)
  char* ws = (char*)d_ws;
  int* counts  = (int*)ws;
  int* rowlist = (int*)(ws + 4096);
  const size_t MB = 1u << 20;
  unsigned short* WT0 = (unsigned short*)(ws + 1*MB);
  unsigned short* WT1 = (unsigned short*)(ws + 2*MB);
  unsigned short* WT2 = (unsigned short*)(ws + 10*MB);
  unsigned short* h1  = (unsigned short*)(ws + 14*MB);
  unsigned short* h2  = (unsigned short*)(ws + 46*MB);
  unsigned short* X0h = (unsigned short*)(ws + 46*MB);  // dead before h2 written

  k_init   <<<1, 64, 0, stream>>>(counts);
  k_compact<<<RT/256, 256, 0, stream>>>(seps, counts, rowlist);

  k_transpose<D0, H1><<<dim3(D0/32, H1/32, NNET), 256, 0, stream>>>(W0, WT0);
  k_transpose<H1, H2><<<dim3(H1/32, H2/32, NNET), 256, 0, stream>>>(W1, WT1);
  k_transpose<H2, H3><<<dim3(H2/32, H3/32, NNET), 256, 0, stream>>>(W2, WT2);
  k_gather0<<<dim3(RT/16, NNET), 256, 0, stream>>>(inputs, counts, rowlist, X0h);

  k_mlp<D0, H1, 1, 0><<<dim3(RT/128, H1/128, NNET), 256, 0, stream>>>(
      X0h, WT0, b0, counts, rowlist, h1, nullptr);
  k_mlp<H1, H2, 1, 0><<<dim3(RT/128, H2/128, NNET), 256, 0, stream>>>(
      h1, WT1, b1, counts, rowlist, h2, nullptr);
  k_mlp<H2, H3, 0, 1><<<dim3(RT/128, H3/128, NNET), 256, 0, stream>>>(
      h2, WT2, b2, counts, rowlist, nullptr, out);
}